// Round 9
// baseline (484.757 us; speedup 1.0000x reference)
//
#include <hip/hip_runtime.h>
#include <math.h>

#define B_ 8
#define C_ 64
#define H_ 50
#define W_ 65
#define N_ 3250
#define NP_ 3264            // padded positions (51*64)
#define SIDE_ 57.0f
#define EPS_ 1e-5f

typedef __attribute__((ext_vector_type(4))) float f32x4;
typedef __attribute__((ext_vector_type(8))) short s16x8;

__device__ __forceinline__ unsigned short rne_bf16(float f) {
    unsigned u = __builtin_bit_cast(unsigned, f);
    u += 0x7FFFu + ((u >> 16) & 1u);
    return (unsigned short)(u >> 16);
}
__device__ __forceinline__ float bf16_f(unsigned short h) {
    return __builtin_bit_cast(float, (unsigned)h << 16);
}

#define MFMA16(acc, a, b) \
    (acc) = __builtin_amdgcn_mfma_f32_16x16x32_bf16((a), (b), (acc), 0, 0, 0)

// ---------------- P1: weight prep -> wt[slot=cv*18+khkw*2+chunk][co][kk] split bf16 --
__global__ void k_wprep(const float* __restrict__ wq, const float* __restrict__ wk,
                        const float* __restrict__ wv,
                        unsigned short* __restrict__ wt_hi, unsigned short* __restrict__ wt_lo)
{
    const int idx  = blockIdx.x * 256 + threadIdx.x;    // 110592 total
    const int slot = idx >> 11;
    const int rem  = idx & 2047;
    const int co   = rem >> 5;
    const int kk   = rem & 31;
    const int cvv  = slot / 18;
    const int r2   = slot % 18;
    const int khkw = r2 >> 1;
    const int chunk= r2 & 1;
    const float* wp = (cvv == 0) ? wq : ((cvv == 1) ? wk : wv);
    const float v = wp[co * 576 + (chunk * 32 + kk) * 9 + khkw];
    const unsigned short hh = rne_bf16(v);
    wt_hi[idx] = hh;
    wt_lo[idx] = rne_bf16(v - bf16_f(hh));
}

// ---------------- P2: x prep -> xt[b][row 52][w' 68][ci 64] split bf16, zero halo ----
__global__ __launch_bounds__(256) void k_xprep(
    const float* __restrict__ x,
    unsigned short* __restrict__ xt_hi, unsigned short* __restrict__ xt_lo)
{
    const int row = blockIdx.x;        // 0..51 (= h+1)
    const int b   = blockIdx.y;
    const int t   = threadIdx.x;
    __shared__ float xls[64 * 66];
    const size_t ob = (size_t)(b * 52 + row) * 68 * 64;
    if (row == 0 || row == 51) {
        for (int s = t; s < 68 * 64; s += 256) { xt_hi[ob + s] = 0; xt_lo[ob + s] = 0; }
        return;
    }
    const int h = row - 1;
    for (int s = t; s < 64 * 65; s += 256) {
        const int ci = s / 65, w = s % 65;
        xls[ci * 66 + w] = x[((size_t)(b * 64 + ci) * 50 + h) * 65 + w];
    }
    __syncthreads();
    for (int s = t; s < 68 * 64; s += 256) {
        const int ci = s & 63, wq = s >> 6;
        const float v = (wq >= 1 && wq <= 65) ? xls[ci * 66 + (wq - 1)] : 0.f;
        const unsigned short hh = rne_bf16(v);
        xt_hi[ob + s] = hh;
        xt_lo[ob + s] = rne_bf16(v - bf16_f(hh));
    }
}

// ---------------- P3: RoPE trig table tt[pos-1][p] = (cos, sin) ---------------------
__global__ void k_trig(const float* __restrict__ fr, float* __restrict__ tt)
{
    const int idx = blockIdx.x * 256 + threadIdx.x;
    if (idx >= 3249 * 32) return;
    const int p = idx & 31;
    const float fi = (float)(idx >> 5);
    const float ty = floorf(fi / SIDE_);
    const float tx = fi - ty * SIDE_;
    float sn, cs;
    sincosf(tx * fr[p] + ty * fr[32 + p], &sn, &cs);
    tt[idx * 2]     = cs;
    tt[idx * 2 + 1] = sn;
}

// ---------------- K1: conv as 9 shifted GEMMs via split-bf16 MFMA -------------------
// grid (50, 8, 3cv), 256 thr (4 waves). wave = n-tile (16 co); 5 m-tiles {0,16,32,48,49}.
__global__ __launch_bounds__(256) void k_conv2(
    const unsigned short* __restrict__ xt_hi, const unsigned short* __restrict__ xt_lo,
    const unsigned short* __restrict__ wt_hi, const unsigned short* __restrict__ wt_lo,
    const float* __restrict__ bq, const float* __restrict__ bk, const float* __restrict__ bv,
    const float* __restrict__ tt,
    float* __restrict__ qr, unsigned short* __restrict__ khg,
    unsigned short* __restrict__ klg, unsigned short* __restrict__ vgT)
{
    const int h  = blockIdx.x;
    const int b  = blockIdx.y;
    const int cv = blockIdx.z;
    const int t  = threadIdx.x;
    const int l  = t & 63;
    const int nt = t >> 6;
    const int c  = l & 15;
    const int g  = l >> 4;

    __shared__ unsigned short vt[64 * 68];

    const float* bp = (cv == 0) ? bq : ((cv == 1) ? bk : bv);
    const int mstart[5] = {0, 16, 32, 48, 49};

    const f32x4 zero4 = {0.f, 0.f, 0.f, 0.f};
    f32x4 acc[5];
#pragma unroll
    for (int mt = 0; mt < 5; ++mt) acc[mt] = zero4;

#pragma unroll 1
    for (int chunk = 0; chunk < 2; ++chunk) {
#pragma unroll 1
        for (int khkw = 0; khkw < 9; ++khkw) {
            const int kh = khkw / 3, kw = khkw % 3;
            const int wb = ((cv * 18 + khkw * 2 + chunk) << 11) + (nt * 16 + c) * 32 + g * 8;
            const s16x8 bh = *(const s16x8*)(wt_hi + wb);
            const s16x8 bl = *(const s16x8*)(wt_lo + wb);
            const int ab0 = (((b * 52 + h + kh) * 68) + c + kw) * 64 + chunk * 32 + g * 8;
#pragma unroll
            for (int mt = 0; mt < 5; ++mt) {
                const int ai = ab0 + mstart[mt] * 64;
                const s16x8 ah = *(const s16x8*)(xt_hi + ai);
                const s16x8 al = *(const s16x8*)(xt_lo + ai);
                MFMA16(acc[mt], ah, bh);
                MFMA16(acc[mt], al, bh);
                MFMA16(acc[mt], ah, bl);
            }
        }
    }

    const int co = nt * 16 + c;
    const float bias = bp[co];

    if (cv == 2) {            // V: LDS transpose -> (B,C,NP) bf16, coalesced store
#pragma unroll
        for (int mt = 0; mt < 5; ++mt)
#pragma unroll
            for (int r = 0; r < 4; ++r) {
                const int mloc = mstart[mt] + g * 4 + r;
                vt[co * 68 + mloc] = rne_bf16(acc[mt][r] + bias);
            }
        __syncthreads();
        for (int s = t; s < 64 * 65; s += 256) {
            const int cc = s / 65, mm = s % 65;
            vgT[(size_t)(b * 64 + cc) * NP_ + h * 65 + mm] = vt[cc * 68 + mm];
        }
        return;
    }

    // q,k: bias + RoPE (pair partner via shfl_xor 1) + store
#pragma unroll
    for (int mt = 0; mt < 5; ++mt)
#pragma unroll
        for (int r = 0; r < 4; ++r) {
            const int mloc = mstart[mt] + g * 4 + r;
            const int pos  = h * 65 + mloc;
            float v = acc[mt][r] + bias;
            const float pr = __shfl_xor(v, 1);
            if (pos > 0) {
                const float2 cs2 = *(const float2*)(tt + ((size_t)(pos - 1) * 32 + (co >> 1)) * 2);
                v = (l & 1) ? (pr * cs2.y + v * cs2.x) : (v * cs2.x - pr * cs2.y);
            }
            if (cv == 0) {
                qr[(size_t)(b * N_ + pos) * 64 + co] = v;
            } else {
                const size_t idx = (size_t)(b * NP_ + pos) * 64 + co;
                const unsigned short hh = rne_bf16(v);
                khg[idx] = hh;
                klg[idx] = rne_bf16(v - bf16_f(hh));
            }
        }
}

// ---------------- K2: flash attention, 4 waves/block each owning a KV chunk ---------
// grid (8, 204), 256 thr. Wave wz covers tiles [wz*13, min(51,wz*13+13)).
// VGPR<=64 (launch_bounds 8 waves/EU): Q-lo frags parked in LDS, re-read per tile
// (asm-opaque offset blocks LICM re-hoisting). LDS 25KB -> 6 blocks/CU = 24 waves/CU.
__global__ __launch_bounds__(256, 8) void k_flash4(
    const float* __restrict__ qr, const unsigned short* __restrict__ khg,
    const unsigned short* __restrict__ klg, const unsigned short* __restrict__ vgT,
    float* __restrict__ oo)
{
    const int b  = blockIdx.x;          // flat%8 == batch -> per-batch XCD pinning
    const int m0 = blockIdx.y << 4;
    const int t  = threadIdx.x;
    const int wz = t >> 6;              // wave id 0..3 (KV chunk)
    const int l  = t & 63;
    const int c  = l & 15;
    const int g  = l >> 4;

    __shared__ char smem[16384];              // pbh[4][1024]us + pbl[4][1024]us | obuf[4][1024]f
    __shared__ unsigned short qlo[4096];      // Q-lo frags [wz][ks][lane][8] = 8KB
    __shared__ float cm[4][16], cl[4][16];    // per-wave (m,l) per row

    unsigned short* pwh = (unsigned short*)(smem + wz * 2048);
    unsigned short* pwl = (unsigned short*)(smem + 8192 + wz * 2048);
    float* obuf = (float*)smem;               // [4][1024], valid after combine barrier

    // Q A-frags: row = lane&15 (m0+c), k = ks*32 + g*8 + j. qh in regs, ql in LDS.
    s16x8 qh[2];
#pragma unroll
    for (int ks = 0; ks < 2; ++ks) {
        const float* qp = qr + ((size_t)(b * N_ + m0 + c) * 64 + ks * 32 + g * 8);
        const f32x4 f0 = *(const f32x4*)qp;
        const f32x4 f1 = *(const f32x4*)(qp + 4);
        s16x8 qlt;
#pragma unroll
        for (int j = 0; j < 4; ++j) {
            const unsigned short h0 = rne_bf16(f0[j]);
            qh[ks][j]     = (short)h0;
            qlt[j]        = (short)rne_bf16(f0[j] - bf16_f(h0));
            const unsigned short h1 = rne_bf16(f1[j]);
            qh[ks][4 + j] = (short)h1;
            qlt[4 + j]    = (short)rne_bf16(f1[j] - bf16_f(h1));
        }
        *(s16x8*)((char*)qlo + (wz * 2 + ks) * 1024 + l * 16) = qlt;
    }

    const f32x4 zero4 = {0.f, 0.f, 0.f, 0.f};
    f32x4 osum[4];
#pragma unroll
    for (int ct = 0; ct < 4; ++ct) osum[ct] = zero4;
    float run_m[4], run_l[4];
#pragma unroll
    for (int r = 0; r < 4; ++r) { run_m[r] = -1e30f; run_l[r] = 0.f; }

    const int tile0 = wz * 13;
    const int tile1 = (wz == 3) ? 51 : tile0 + 13;
    for (int tile = tile0; tile < tile1; ++tile) {
        const int n0 = tile << 6;

        // re-read Q-lo each tile; opaque offset so it can't be hoisted into VGPRs
        int qoff = wz * 2048 + l * 16;
        asm volatile("" : "+v"(qoff));
        const s16x8 ql0 = *(const s16x8*)((const char*)qlo + qoff);
        const s16x8 ql1 = *(const s16x8*)((const char*)qlo + qoff + 1024);

        // ---- S = Q K^T (3-product split) ----
        f32x4 s4[4];
#pragma unroll
        for (int nt = 0; nt < 4; ++nt) s4[nt] = zero4;
#pragma unroll
        for (int ks = 0; ks < 2; ++ks) {
#pragma unroll
            for (int nt = 0; nt < 4; ++nt) {
                const size_t kb = (size_t)(b * NP_ + n0 + nt * 16 + c) * 64 + ks * 32 + g * 8;
                const s16x8 kh = *(const s16x8*)(khg + kb);
                const s16x8 kl = *(const s16x8*)(klg + kb);
                MFMA16(s4[nt], qh[ks], kh);
                MFMA16(s4[nt], ks ? ql1 : ql0, kh);
                MFMA16(s4[nt], qh[ks], kl);
            }
        }

        if (tile == 50) {                  // mask padded columns (only wave 3)
#pragma unroll
            for (int nt = 0; nt < 4; ++nt)
                if (n0 + nt * 16 + c >= N_) {
                    const f32x4 m4 = {-1e30f, -1e30f, -1e30f, -1e30f};
                    s4[nt] = m4;
                }
        }

        // ---- online softmax: row r across the 16 c-lanes of group g ----
        float corr[4];
#pragma unroll
        for (int r = 0; r < 4; ++r) {
            float tm = fmaxf(fmaxf(s4[0][r], s4[1][r]), fmaxf(s4[2][r], s4[3][r]));
            tm = fmaxf(tm, __shfl_xor(tm, 1));
            tm = fmaxf(tm, __shfl_xor(tm, 2));
            tm = fmaxf(tm, __shfl_xor(tm, 4));
            tm = fmaxf(tm, __shfl_xor(tm, 8));
            const float mnew = fmaxf(run_m[r], tm);
            corr[r] = __expf(run_m[r] - mnew);
            float ts = 0.f;
#pragma unroll
            for (int nt = 0; nt < 4; ++nt) {
                const float p = __expf(s4[nt][r] - mnew);
                s4[nt][r] = p;
                ts += p;
            }
            ts += __shfl_xor(ts, 1);
            ts += __shfl_xor(ts, 2);
            ts += __shfl_xor(ts, 4);
            ts += __shfl_xor(ts, 8);
            run_l[r] = run_l[r] * corr[r] + ts;
            run_m[r] = mnew;
        }
#pragma unroll
        for (int ct = 0; ct < 4; ++ct)
#pragma unroll
            for (int r = 0; r < 4; ++r) osum[ct][r] *= corr[r];

        // ---- P split -> per-wave LDS slice (swizzled [m][n]) ----
#pragma unroll
        for (int nt = 0; nt < 4; ++nt)
#pragma unroll
            for (int r = 0; r < 4; ++r) {
                const int m   = g * 4 + r;
                const int off = m * 128 + ((((nt * 16 + c) * 2)) ^ ((m & 7) << 4));
                const float p = s4[nt][r];
                const unsigned short ph = rne_bf16(p);
                *(unsigned short*)((char*)pwh + off) = ph;
                *(unsigned short*)((char*)pwl + off) = rne_bf16(p - bf16_f(ph));
            }

        // ---- O += P V ----
#pragma unroll
        for (int ks = 0; ks < 2; ++ks) {
            const int aoff = c * 128 + (((ks * 64 + g * 16)) ^ ((c & 7) << 4));
            const s16x8 pah = *(const s16x8*)((const char*)pwh + aoff);
            const s16x8 pal = *(const s16x8*)((const char*)pwl + aoff);
#pragma unroll
            for (int ct = 0; ct < 4; ++ct) {
                const size_t vb = (size_t)(b * 64 + ct * 16 + c) * NP_ + n0 + ks * 32 + g * 8;
                const s16x8 vf = *(const s16x8*)(vgT + vb);
                MFMA16(osum[ct], pah, vf);
                MFMA16(osum[ct], pal, vf);
            }
        }
    }

    // ---- combine the 4 KV chunks (row-local math only) ----
    if (c == 0) {
#pragma unroll
        for (int r = 0; r < 4; ++r) {
            cm[wz][g * 4 + r] = run_m[r];
            cl[wz][g * 4 + r] = run_l[r];
        }
    }
    __syncthreads();   // all P reads done + cm/cl visible -> safe to reuse smem as obuf
#pragma unroll
    for (int r = 0; r < 4; ++r) {
        const int row = g * 4 + r;
        const float M = fmaxf(fmaxf(cm[0][row], cm[1][row]), fmaxf(cm[2][row], cm[3][row]));
        const float w = __expf(run_m[r] - M);
#pragma unroll
        for (int ct = 0; ct < 4; ++ct)
            obuf[wz * 1024 + row * 64 + ct * 16 + c] = osum[ct][r] * w;
    }
    __syncthreads();
    for (int i = t; i < 1024; i += 256) {
        const int row = i >> 6;
        const int m   = m0 + row;
        if (m >= N_) continue;
        const float M = fmaxf(fmaxf(cm[0][row], cm[1][row]), fmaxf(cm[2][row], cm[3][row]));
        float L = 0.f, o = 0.f;
#pragma unroll
        for (int z = 0; z < 4; ++z) {
            L += cl[z][row] * __expf(cm[z][row] - M);
            o += obuf[z * 1024 + i];
        }
        oo[(size_t)(b * N_ + m) * 64 + (i & 63)] = o / L;
    }
}

// ---------------- K3: y = gamma*x + O^T, per-block partial sums (no atomics) --------
__global__ __launch_bounds__(256) void k_bnstats(
    const float* __restrict__ x, const float* __restrict__ oo,
    const float* __restrict__ gamma, float* __restrict__ yy, float* __restrict__ part)
{
    const int b    = blockIdx.y;
    const int m0   = blockIdx.x * 64;
    const int t    = threadIdx.x;
    const int lane = t & 63;
    const int blk  = blockIdx.y * 51 + blockIdx.x;
    __shared__ float ot[64 * 65];
    const float gm = gamma[0];
    {
        const int r4 = t >> 6;
#pragma unroll
        for (int i = 0; i < 16; ++i) {
            const int row = r4 + i * 4;
            const int m   = m0 + row;
            ot[row * 65 + lane] = (m < N_) ? oo[((size_t)b * N_ + m) * 64 + lane] : 0.f;
        }
    }
    __syncthreads();
    const int  m     = m0 + lane;
    const bool valid = (m < N_);
#pragma unroll
    for (int i = 0; i < 16; ++i) {
        const int c = (t >> 6) + (i << 2);
        float y = 0.f;
        if (valid) {
            const float xv = x[(size_t)(b * 64 + c) * N_ + m];
            y = gm * xv + ot[lane * 65 + c];
            yy[(size_t)(b * 64 + c) * N_ + m] = y;
        }
        float s1 = y, s2 = y * y;
#pragma unroll
        for (int d = 1; d < 64; d <<= 1) { s1 += __shfl_xor(s1, d); s2 += __shfl_xor(s2, d); }
        if (lane == 0) {
            part[(size_t)blk * 128 + c]      = s1;
            part[(size_t)blk * 128 + 64 + c] = s2;
        }
    }
}

// ---------------- K4: reduce partials, finalize scale/shift -------------------------
__global__ void k_bnfin(const float* __restrict__ part, const float* __restrict__ bnw,
                        const float* __restrict__ bnb, float* __restrict__ ss)
{
    const int c = threadIdx.x;              // 64
    float s1 = 0.f, s2 = 0.f;
    for (int k = 0; k < 408; ++k) {
        s1 += part[(size_t)k * 128 + c];
        s2 += part[(size_t)k * 128 + 64 + c];
    }
    const float cnt  = (float)(B_ * N_);
    const float mean = s1 / cnt;
    const float var  = s2 / cnt - mean * mean;
    const float sc   = bnw[c] * rsqrtf(var + EPS_);
    ss[c]      = sc;
    ss[64 + c] = bnb[c] - mean * sc;
}

// ---------------- K5: apply BN -------------------------------------------------------
__global__ __launch_bounds__(256) void k_bnapply(
    const float* __restrict__ yy, const float* __restrict__ ss, float* __restrict__ out)
{
    const int total = B_ * C_ * N_;
    for (int e = blockIdx.x * 256 + threadIdx.x; e < total; e += gridDim.x * 256) {
        const int c = (e / N_) & 63;
        out[e] = yy[e] * ss[c] + ss[64 + c];
    }
}

// ---------------- launch -------------------------------------------------------------
extern "C" void kernel_launch(void* const* d_in, const int* in_sizes, int n_in,
                              void* d_out, int out_size, void* d_ws, size_t ws_size,
                              hipStream_t stream) {
    const float* x     = (const float*)d_in[0];
    const float* wq    = (const float*)d_in[1];
    const float* bq    = (const float*)d_in[2];
    const float* wk    = (const float*)d_in[3];
    const float* bk    = (const float*)d_in[4];
    const float* wv    = (const float*)d_in[5];
    const float* bv    = (const float*)d_in[6];
    const float* fr    = (const float*)d_in[7];
    const float* gamma = (const float*)d_in[8];
    const float* bnw   = (const float*)d_in[9];
    const float* bnb   = (const float*)d_in[10];

    // ws layout (floats), total 6,352,064 f = 25.4 MB (<= proven 26.6 MB budget)
    float* wsf = (float*)d_ws;
    float*          qr    = wsf;                                  // 1,664,000
    unsigned short* khg   = (unsigned short*)(wsf + 1664000);     // 835,584 f each
    unsigned short* klg   = (unsigned short*)(wsf + 2499584);
    unsigned short* vgT   = (unsigned short*)(wsf + 3335168);
    float*          regB  = wsf + 4170752;                        // 2,128,960 f region
    unsigned short* xt_hi = (unsigned short*)regB;                // conv phase
    unsigned short* xt_lo = (unsigned short*)(regB + 905216);
    unsigned short* wt_hi = (unsigned short*)(regB + 1810432);
    unsigned short* wt_lo = (unsigned short*)(regB + 1865728);
    float*          tt    = regB + 1921024;                       // 207,936
    float*          oo    = regB;                                 // flash phase (1,664,000)
    float*          part  = wsf + 6299712;                        // 52,224
    float*          ss    = wsf + 6351936;                        // 128
    float*          yy    = qr;                                   // reuse after flash
    float*          outp  = (float*)d_out;

    k_wprep<<<432, 256, 0, stream>>>(wq, wk, wv, wt_hi, wt_lo);
    k_xprep<<<dim3(52, 8), 256, 0, stream>>>(x, xt_hi, xt_lo);
    k_trig<<<407, 256, 0, stream>>>(fr, tt);
    k_conv2<<<dim3(50, 8, 3), 256, 0, stream>>>(xt_hi, xt_lo, wt_hi, wt_lo,
                                                bq, bk, bv, tt, qr, khg, klg, vgT);
    k_flash4<<<dim3(8, 204), 256, 0, stream>>>(qr, khg, klg, vgT, oo);
    k_bnstats<<<dim3(51, 8), 256, 0, stream>>>(x, oo, gamma, yy, part);
    k_bnfin<<<1, 64, 0, stream>>>(part, bnw, bnb, ss);
    k_bnapply<<<1024, 256, 0, stream>>>(yy, ss, outp);
}

// Round 10
// 389.010 us; speedup vs baseline: 1.2461x; 1.2461x over previous
//
#include <hip/hip_runtime.h>
#include <math.h>

#define B_ 8
#define C_ 64
#define H_ 50
#define W_ 65
#define N_ 3250
#define NP_ 3264            // padded positions (51*64)
#define SIDE_ 57.0f
#define EPS_ 1e-5f

typedef __attribute__((ext_vector_type(4))) float f32x4;
typedef __attribute__((ext_vector_type(8))) short s16x8;

__device__ __forceinline__ unsigned short rne_bf16(float f) {
    unsigned u = __builtin_bit_cast(unsigned, f);
    u += 0x7FFFu + ((u >> 16) & 1u);
    return (unsigned short)(u >> 16);
}
__device__ __forceinline__ float bf16_f(unsigned short h) {
    return __builtin_bit_cast(float, (unsigned)h << 16);
}

#define MFMA16(acc, a, b) \
    (acc) = __builtin_amdgcn_mfma_f32_16x16x32_bf16((a), (b), (acc), 0, 0, 0)

// ---------------- P1: weight prep -> wt[slot=cv*18+khkw*2+chunk][co][kk] split bf16 --
__global__ void k_wprep(const float* __restrict__ wq, const float* __restrict__ wk,
                        const float* __restrict__ wv,
                        unsigned short* __restrict__ wt_hi, unsigned short* __restrict__ wt_lo)
{
    const int idx  = blockIdx.x * 256 + threadIdx.x;    // 110592 total
    const int slot = idx >> 11;
    const int rem  = idx & 2047;
    const int co   = rem >> 5;
    const int kk   = rem & 31;
    const int cvv  = slot / 18;
    const int r2   = slot % 18;
    const int khkw = r2 >> 1;
    const int chunk= r2 & 1;
    const float* wp = (cvv == 0) ? wq : ((cvv == 1) ? wk : wv);
    const float v = wp[co * 576 + (chunk * 32 + kk) * 9 + khkw];
    const unsigned short hh = rne_bf16(v);
    wt_hi[idx] = hh;
    wt_lo[idx] = rne_bf16(v - bf16_f(hh));
}

// ---------------- P2: x prep -> xt[b][row 52][w' 68][ci 64] split bf16, zero halo ----
__global__ __launch_bounds__(256) void k_xprep(
    const float* __restrict__ x,
    unsigned short* __restrict__ xt_hi, unsigned short* __restrict__ xt_lo)
{
    const int row = blockIdx.x;        // 0..51 (= h+1)
    const int b   = blockIdx.y;
    const int t   = threadIdx.x;
    __shared__ float xls[64 * 66];
    const size_t ob = (size_t)(b * 52 + row) * 68 * 64;
    if (row == 0 || row == 51) {
        for (int s = t; s < 68 * 64; s += 256) { xt_hi[ob + s] = 0; xt_lo[ob + s] = 0; }
        return;
    }
    const int h = row - 1;
    for (int s = t; s < 64 * 65; s += 256) {
        const int ci = s / 65, w = s % 65;
        xls[ci * 66 + w] = x[((size_t)(b * 64 + ci) * 50 + h) * 65 + w];
    }
    __syncthreads();
    for (int s = t; s < 68 * 64; s += 256) {
        const int ci = s & 63, wq = s >> 6;
        const float v = (wq >= 1 && wq <= 65) ? xls[ci * 66 + (wq - 1)] : 0.f;
        const unsigned short hh = rne_bf16(v);
        xt_hi[ob + s] = hh;
        xt_lo[ob + s] = rne_bf16(v - bf16_f(hh));
    }
}

// ---------------- P3: RoPE trig table tt[pos-1][p] = (cos, sin) ---------------------
__global__ void k_trig(const float* __restrict__ fr, float* __restrict__ tt)
{
    const int idx = blockIdx.x * 256 + threadIdx.x;
    if (idx >= 3249 * 32) return;
    const int p = idx & 31;
    const float fi = (float)(idx >> 5);
    const float ty = floorf(fi / SIDE_);
    const float tx = fi - ty * SIDE_;
    float sn, cs;
    sincosf(tx * fr[p] + ty * fr[32 + p], &sn, &cs);
    tt[idx * 2]     = cs;
    tt[idx * 2 + 1] = sn;
}

// ---------------- K1: conv as 9 shifted GEMMs via split-bf16 MFMA -------------------
// grid (50, 8, 3cv), 256 thr (4 waves). wave = n-tile (16 co); 5 m-tiles {0,16,32,48,49}.
__global__ __launch_bounds__(256) void k_conv2(
    const unsigned short* __restrict__ xt_hi, const unsigned short* __restrict__ xt_lo,
    const unsigned short* __restrict__ wt_hi, const unsigned short* __restrict__ wt_lo,
    const float* __restrict__ bq, const float* __restrict__ bk, const float* __restrict__ bv,
    const float* __restrict__ tt,
    float* __restrict__ qr, unsigned short* __restrict__ khg,
    unsigned short* __restrict__ klg, unsigned short* __restrict__ vgT)
{
    const int h  = blockIdx.x;
    const int b  = blockIdx.y;
    const int cv = blockIdx.z;
    const int t  = threadIdx.x;
    const int l  = t & 63;
    const int nt = t >> 6;
    const int c  = l & 15;
    const int g  = l >> 4;

    __shared__ unsigned short vt[64 * 68];

    const float* bp = (cv == 0) ? bq : ((cv == 1) ? bk : bv);
    const int mstart[5] = {0, 16, 32, 48, 49};

    const f32x4 zero4 = {0.f, 0.f, 0.f, 0.f};
    f32x4 acc[5];
#pragma unroll
    for (int mt = 0; mt < 5; ++mt) acc[mt] = zero4;

#pragma unroll 1
    for (int chunk = 0; chunk < 2; ++chunk) {
#pragma unroll 1
        for (int khkw = 0; khkw < 9; ++khkw) {
            const int kh = khkw / 3, kw = khkw % 3;
            const int wb = ((cv * 18 + khkw * 2 + chunk) << 11) + (nt * 16 + c) * 32 + g * 8;
            const s16x8 bh = *(const s16x8*)(wt_hi + wb);
            const s16x8 bl = *(const s16x8*)(wt_lo + wb);
            const int ab0 = (((b * 52 + h + kh) * 68) + c + kw) * 64 + chunk * 32 + g * 8;
#pragma unroll
            for (int mt = 0; mt < 5; ++mt) {
                const int ai = ab0 + mstart[mt] * 64;
                const s16x8 ah = *(const s16x8*)(xt_hi + ai);
                const s16x8 al = *(const s16x8*)(xt_lo + ai);
                MFMA16(acc[mt], ah, bh);
                MFMA16(acc[mt], al, bh);
                MFMA16(acc[mt], ah, bl);
            }
        }
    }

    const int co = nt * 16 + c;
    const float bias = bp[co];

    if (cv == 2) {            // V: LDS transpose -> (B,C,NP) bf16, coalesced store
#pragma unroll
        for (int mt = 0; mt < 5; ++mt)
#pragma unroll
            for (int r = 0; r < 4; ++r) {
                const int mloc = mstart[mt] + g * 4 + r;
                vt[co * 68 + mloc] = rne_bf16(acc[mt][r] + bias);
            }
        __syncthreads();
        for (int s = t; s < 64 * 65; s += 256) {
            const int cc = s / 65, mm = s % 65;
            vgT[(size_t)(b * 64 + cc) * NP_ + h * 65 + mm] = vt[cc * 68 + mm];
        }
        return;
    }

    // q,k: bias + RoPE (pair partner via shfl_xor 1) + store
#pragma unroll
    for (int mt = 0; mt < 5; ++mt)
#pragma unroll
        for (int r = 0; r < 4; ++r) {
            const int mloc = mstart[mt] + g * 4 + r;
            const int pos  = h * 65 + mloc;
            float v = acc[mt][r] + bias;
            const float pr = __shfl_xor(v, 1);
            if (pos > 0) {
                const float2 cs2 = *(const float2*)(tt + ((size_t)(pos - 1) * 32 + (co >> 1)) * 2);
                v = (l & 1) ? (pr * cs2.y + v * cs2.x) : (v * cs2.x - pr * cs2.y);
            }
            if (cv == 0) {
                qr[(size_t)(b * N_ + pos) * 64 + co] = v;
            } else {
                const size_t idx = (size_t)(b * NP_ + pos) * 64 + co;
                const unsigned short hh = rne_bf16(v);
                khg[idx] = hh;
                klg[idx] = rne_bf16(v - bf16_f(hh));
            }
        }
}

// ---------------- K2: flash attention, LDS-staged KV shared by 8 waves --------------
// grid (8, 26), 512 thr. Wave wz owns q-rows [by*128 + wz*16, +16); all waves iterate
// all 51 KV tiles. Per tile: 512 threads stage K-hi/K-lo/V (24KB, coalesced 16B/thread)
// into XOR-swizzled LDS (byte ^ ((row&7)<<4)); fragments via ds_read_b128.
// Math identical to validated flash4 (same fragment indices).
__global__ __launch_bounds__(512) void k_flash5(
    const float* __restrict__ qr, const unsigned short* __restrict__ khg,
    const unsigned short* __restrict__ klg, const unsigned short* __restrict__ vgT,
    float* __restrict__ oo)
{
    const int b  = blockIdx.x;          // flat%8 == batch -> per-batch XCD pinning
    const int t  = threadIdx.x;
    const int wz = t >> 6;              // wave id 0..7
    const int l  = t & 63;
    const int c  = l & 15;
    const int g  = l >> 4;
    const int m0 = blockIdx.y * 128 + wz * 16;

    __shared__ __align__(16) unsigned short kbh[4096];   // 8KB K-hi [64key][64]swz
    __shared__ __align__(16) unsigned short kbl[4096];   // 8KB K-lo
    __shared__ __align__(16) unsigned short vb[4096];    // 8KB V  [64ch][64key-chunk]swz
    __shared__ __align__(16) char psmem[32768];          // per-wave P hi/lo (4KB each)

    char* pwh = psmem + wz * 4096;
    char* pwl = psmem + wz * 4096 + 2048;

    // Q A-frags: row = lane&15 (m0+c), k = ks*32 + g*8 + j
    s16x8 qh[2], ql[2];
#pragma unroll
    for (int ks = 0; ks < 2; ++ks) {
        const float* qp = qr + ((size_t)(b * N_ + m0 + c) * 64 + ks * 32 + g * 8);
        const f32x4 f0 = *(const f32x4*)qp;
        const f32x4 f1 = *(const f32x4*)(qp + 4);
#pragma unroll
        for (int j = 0; j < 4; ++j) {
            const unsigned short h0 = rne_bf16(f0[j]);
            qh[ks][j]     = (short)h0;
            ql[ks][j]     = (short)rne_bf16(f0[j] - bf16_f(h0));
            const unsigned short h1 = rne_bf16(f1[j]);
            qh[ks][4 + j] = (short)h1;
            ql[ks][4 + j] = (short)rne_bf16(f1[j] - bf16_f(h1));
        }
    }

    const f32x4 zero4 = {0.f, 0.f, 0.f, 0.f};
    f32x4 osum[4];
#pragma unroll
    for (int ct = 0; ct < 4; ++ct) osum[ct] = zero4;
    float run_m[4], run_l[4];
#pragma unroll
    for (int r = 0; r < 4; ++r) { run_m[r] = -1e30f; run_l[r] = 0.f; }

    // staging indices: thread t handles 16B slot (row = t>>3, chunk = t&7)
    const int srow   = t >> 3;
    const int schunk = t & 7;
    const int sdst   = (srow * 128 + schunk * 16) ^ ((srow & 7) << 4);

    for (int tile = 0; tile < 51; ++tile) {
        const int n0 = tile << 6;

        __syncthreads();   // previous tile's K/V reads complete before overwrite
        {
            const unsigned short* ksrc = khg + ((size_t)(b * NP_) + n0) * 64;
            const unsigned short* lsrc = klg + ((size_t)(b * NP_) + n0) * 64;
            const unsigned short* vsrc = vgT + (size_t)(b * 64 + srow) * NP_ + n0;
            *(s16x8*)((char*)kbh + sdst) = *(const s16x8*)(ksrc + t * 8);
            *(s16x8*)((char*)kbl + sdst) = *(const s16x8*)(lsrc + t * 8);
            *(s16x8*)((char*)vb  + sdst) = *(const s16x8*)(vsrc + schunk * 8);
        }
        __syncthreads();   // tile staged

        // ---- S = Q K^T (3-product split), K frags from LDS ----
        f32x4 s4[4];
#pragma unroll
        for (int nt = 0; nt < 4; ++nt) s4[nt] = zero4;
#pragma unroll
        for (int ks = 0; ks < 2; ++ks) {
#pragma unroll
            for (int nt = 0; nt < 4; ++nt) {
                const int krow = nt * 16 + c;
                const int koff = (krow * 128 + ks * 64 + g * 16) ^ ((krow & 7) << 4);
                const s16x8 kh = *(const s16x8*)((const char*)kbh + koff);
                const s16x8 kl = *(const s16x8*)((const char*)kbl + koff);
                MFMA16(s4[nt], qh[ks], kh);
                MFMA16(s4[nt], ql[ks], kh);
                MFMA16(s4[nt], qh[ks], kl);
            }
        }

        if (tile == 50) {                  // mask padded key columns
#pragma unroll
            for (int nt = 0; nt < 4; ++nt)
                if (n0 + nt * 16 + c >= N_) {
                    const f32x4 m4 = {-1e30f, -1e30f, -1e30f, -1e30f};
                    s4[nt] = m4;
                }
        }

        // ---- online softmax: row r across the 16 c-lanes of group g ----
        float corr[4];
#pragma unroll
        for (int r = 0; r < 4; ++r) {
            float tm = fmaxf(fmaxf(s4[0][r], s4[1][r]), fmaxf(s4[2][r], s4[3][r]));
            tm = fmaxf(tm, __shfl_xor(tm, 1));
            tm = fmaxf(tm, __shfl_xor(tm, 2));
            tm = fmaxf(tm, __shfl_xor(tm, 4));
            tm = fmaxf(tm, __shfl_xor(tm, 8));
            const float mnew = fmaxf(run_m[r], tm);
            corr[r] = __expf(run_m[r] - mnew);
            float ts = 0.f;
#pragma unroll
            for (int nt = 0; nt < 4; ++nt) {
                const float p = __expf(s4[nt][r] - mnew);
                s4[nt][r] = p;
                ts += p;
            }
            ts += __shfl_xor(ts, 1);
            ts += __shfl_xor(ts, 2);
            ts += __shfl_xor(ts, 4);
            ts += __shfl_xor(ts, 8);
            run_l[r] = run_l[r] * corr[r] + ts;
            run_m[r] = mnew;
        }
#pragma unroll
        for (int ct = 0; ct < 4; ++ct)
#pragma unroll
            for (int r = 0; r < 4; ++r) osum[ct][r] *= corr[r];

        // ---- P split -> per-wave LDS slice (swizzled [m][n]) ----
#pragma unroll
        for (int nt = 0; nt < 4; ++nt)
#pragma unroll
            for (int r = 0; r < 4; ++r) {
                const int m   = g * 4 + r;
                const int off = m * 128 + ((((nt * 16 + c) * 2)) ^ ((m & 7) << 4));
                const float p = s4[nt][r];
                const unsigned short ph = rne_bf16(p);
                *(unsigned short*)(pwh + off) = ph;
                *(unsigned short*)(pwl + off) = rne_bf16(p - bf16_f(ph));
            }

        // ---- O += P V, V frags from LDS ----
#pragma unroll
        for (int ks = 0; ks < 2; ++ks) {
            const int aoff = c * 128 + (((ks * 64 + g * 16)) ^ ((c & 7) << 4));
            const s16x8 pah = *(const s16x8*)(pwh + aoff);
            const s16x8 pal = *(const s16x8*)(pwl + aoff);
#pragma unroll
            for (int ct = 0; ct < 4; ++ct) {
                const int vrow = ct * 16 + c;
                const int voff = (vrow * 128 + ks * 64 + g * 16) ^ ((vrow & 7) << 4);
                const s16x8 vf = *(const s16x8*)((const char*)vb + voff);
                MFMA16(osum[ct], pah, vf);
                MFMA16(osum[ct], pal, vf);
            }
        }
    }

    // ---- epilogue: each wave owns its rows; direct normalize + store ----
#pragma unroll
    for (int ct = 0; ct < 4; ++ct)
#pragma unroll
        for (int r = 0; r < 4; ++r) {
            const int m = m0 + g * 4 + r;          // C/D row = g*4+r, col = ct*16+c
            if (m < N_) oo[(size_t)(b * N_ + m) * 64 + ct * 16 + c] = osum[ct][r] / run_l[r];
        }
}

// ---------------- K3: y = gamma*x + O^T, per-block partial sums (no atomics) --------
__global__ __launch_bounds__(256) void k_bnstats(
    const float* __restrict__ x, const float* __restrict__ oo,
    const float* __restrict__ gamma, float* __restrict__ yy, float* __restrict__ part)
{
    const int b    = blockIdx.y;
    const int m0   = blockIdx.x * 64;
    const int t    = threadIdx.x;
    const int lane = t & 63;
    const int blk  = blockIdx.y * 51 + blockIdx.x;
    __shared__ float ot[64 * 65];
    const float gm = gamma[0];
    {
        const int r4 = t >> 6;
#pragma unroll
        for (int i = 0; i < 16; ++i) {
            const int row = r4 + i * 4;
            const int m   = m0 + row;
            ot[row * 65 + lane] = (m < N_) ? oo[((size_t)b * N_ + m) * 64 + lane] : 0.f;
        }
    }
    __syncthreads();
    const int  m     = m0 + lane;
    const bool valid = (m < N_);
#pragma unroll
    for (int i = 0; i < 16; ++i) {
        const int c = (t >> 6) + (i << 2);
        float y = 0.f;
        if (valid) {
            const float xv = x[(size_t)(b * 64 + c) * N_ + m];
            y = gm * xv + ot[lane * 65 + c];
            yy[(size_t)(b * 64 + c) * N_ + m] = y;
        }
        float s1 = y, s2 = y * y;
#pragma unroll
        for (int d = 1; d < 64; d <<= 1) { s1 += __shfl_xor(s1, d); s2 += __shfl_xor(s2, d); }
        if (lane == 0) {
            part[(size_t)blk * 128 + c]      = s1;
            part[(size_t)blk * 128 + 64 + c] = s2;
        }
    }
}

// ---------------- K4: reduce partials, finalize scale/shift -------------------------
__global__ void k_bnfin(const float* __restrict__ part, const float* __restrict__ bnw,
                        const float* __restrict__ bnb, float* __restrict__ ss)
{
    const int c = threadIdx.x;              // 64
    float s1 = 0.f, s2 = 0.f;
    for (int k = 0; k < 408; ++k) {
        s1 += part[(size_t)k * 128 + c];
        s2 += part[(size_t)k * 128 + 64 + c];
    }
    const float cnt  = (float)(B_ * N_);
    const float mean = s1 / cnt;
    const float var  = s2 / cnt - mean * mean;
    const float sc   = bnw[c] * rsqrtf(var + EPS_);
    ss[c]      = sc;
    ss[64 + c] = bnb[c] - mean * sc;
}

// ---------------- K5: apply BN -------------------------------------------------------
__global__ __launch_bounds__(256) void k_bnapply(
    const float* __restrict__ yy, const float* __restrict__ ss, float* __restrict__ out)
{
    const int total = B_ * C_ * N_;
    for (int e = blockIdx.x * 256 + threadIdx.x; e < total; e += gridDim.x * 256) {
        const int c = (e / N_) & 63;
        out[e] = yy[e] * ss[c] + ss[64 + c];
    }
}

// ---------------- launch -------------------------------------------------------------
extern "C" void kernel_launch(void* const* d_in, const int* in_sizes, int n_in,
                              void* d_out, int out_size, void* d_ws, size_t ws_size,
                              hipStream_t stream) {
    const float* x     = (const float*)d_in[0];
    const float* wq    = (const float*)d_in[1];
    const float* bq    = (const float*)d_in[2];
    const float* wk    = (const float*)d_in[3];
    const float* bk    = (const float*)d_in[4];
    const float* wv    = (const float*)d_in[5];
    const float* bv    = (const float*)d_in[6];
    const float* fr    = (const float*)d_in[7];
    const float* gamma = (const float*)d_in[8];
    const float* bnw   = (const float*)d_in[9];
    const float* bnb   = (const float*)d_in[10];

    // ws layout (floats), total 6,352,064 f = 25.4 MB (<= proven 26.6 MB budget)
    float* wsf = (float*)d_ws;
    float*          qr    = wsf;                                  // 1,664,000
    unsigned short* khg   = (unsigned short*)(wsf + 1664000);     // 835,584 f each
    unsigned short* klg   = (unsigned short*)(wsf + 2499584);
    unsigned short* vgT   = (unsigned short*)(wsf + 3335168);
    float*          regB  = wsf + 4170752;                        // 2,128,960 f region
    unsigned short* xt_hi = (unsigned short*)regB;                // conv phase
    unsigned short* xt_lo = (unsigned short*)(regB + 905216);
    unsigned short* wt_hi = (unsigned short*)(regB + 1810432);
    unsigned short* wt_lo = (unsigned short*)(regB + 1865728);
    float*          tt    = regB + 1921024;                       // 207,936
    float*          oo    = regB;                                 // flash phase (1,664,000)
    float*          part  = wsf + 6299712;                        // 52,224
    float*          ss    = wsf + 6351936;                        // 128
    float*          yy    = qr;                                   // reuse after flash
    float*          outp  = (float*)d_out;

    k_wprep<<<432, 256, 0, stream>>>(wq, wk, wv, wt_hi, wt_lo);
    k_xprep<<<dim3(52, 8), 256, 0, stream>>>(x, xt_hi, xt_lo);
    k_trig<<<407, 256, 0, stream>>>(fr, tt);
    k_conv2<<<dim3(50, 8, 3), 256, 0, stream>>>(xt_hi, xt_lo, wt_hi, wt_lo,
                                                bq, bk, bv, tt, qr, khg, klg, vgT);
    k_flash5<<<dim3(8, 26), 512, 0, stream>>>(qr, khg, klg, vgT, oo);
    k_bnstats<<<dim3(51, 8), 256, 0, stream>>>(x, oo, gamma, yy, part);
    k_bnfin<<<1, 64, 0, stream>>>(part, bnw, bnb, ss);
    k_bnapply<<<1024, 256, 0, stream>>>(yy, ss, outp);
}

// Round 11
// 369.896 us; speedup vs baseline: 1.3105x; 1.0517x over previous
//
#include <hip/hip_runtime.h>
#include <math.h>

#define B_ 8
#define C_ 64
#define H_ 50
#define W_ 65
#define N_ 3250
#define NP_ 3264            // padded positions (51*64)
#define SIDE_ 57.0f
#define EPS_ 1e-5f

typedef __attribute__((ext_vector_type(4))) float f32x4;
typedef __attribute__((ext_vector_type(8))) short s16x8;

__device__ __forceinline__ unsigned short rne_bf16(float f) {
    unsigned u = __builtin_bit_cast(unsigned, f);
    u += 0x7FFFu + ((u >> 16) & 1u);
    return (unsigned short)(u >> 16);
}
__device__ __forceinline__ float bf16_f(unsigned short h) {
    return __builtin_bit_cast(float, (unsigned)h << 16);
}

#define MFMA16(acc, a, b) \
    (acc) = __builtin_amdgcn_mfma_f32_16x16x32_bf16((a), (b), (acc), 0, 0, 0)

// ---------------- P1: weight prep -> wt[slot=cv*18+khkw*2+chunk][co][kk] split bf16 --
__global__ void k_wprep(const float* __restrict__ wq, const float* __restrict__ wk,
                        const float* __restrict__ wv,
                        unsigned short* __restrict__ wt_hi, unsigned short* __restrict__ wt_lo)
{
    const int idx  = blockIdx.x * 256 + threadIdx.x;    // 110592 total
    const int slot = idx >> 11;
    const int rem  = idx & 2047;
    const int co   = rem >> 5;
    const int kk   = rem & 31;
    const int cvv  = slot / 18;
    const int r2   = slot % 18;
    const int khkw = r2 >> 1;
    const int chunk= r2 & 1;
    const float* wp = (cvv == 0) ? wq : ((cvv == 1) ? wk : wv);
    const float v = wp[co * 576 + (chunk * 32 + kk) * 9 + khkw];
    const unsigned short hh = rne_bf16(v);
    wt_hi[idx] = hh;
    wt_lo[idx] = rne_bf16(v - bf16_f(hh));
}

// ---------------- P2: x prep -> xt[b][row 52][w' 68][ci 64] split bf16, zero halo ----
__global__ __launch_bounds__(256) void k_xprep(
    const float* __restrict__ x,
    unsigned short* __restrict__ xt_hi, unsigned short* __restrict__ xt_lo)
{
    const int row = blockIdx.x;        // 0..51 (= h+1)
    const int b   = blockIdx.y;
    const int t   = threadIdx.x;
    __shared__ float xls[64 * 66];
    const size_t ob = (size_t)(b * 52 + row) * 68 * 64;
    if (row == 0 || row == 51) {
        for (int s = t; s < 68 * 64; s += 256) { xt_hi[ob + s] = 0; xt_lo[ob + s] = 0; }
        return;
    }
    const int h = row - 1;
    for (int s = t; s < 64 * 65; s += 256) {
        const int ci = s / 65, w = s % 65;
        xls[ci * 66 + w] = x[((size_t)(b * 64 + ci) * 50 + h) * 65 + w];
    }
    __syncthreads();
    for (int s = t; s < 68 * 64; s += 256) {
        const int ci = s & 63, wq = s >> 6;
        const float v = (wq >= 1 && wq <= 65) ? xls[ci * 66 + (wq - 1)] : 0.f;
        const unsigned short hh = rne_bf16(v);
        xt_hi[ob + s] = hh;
        xt_lo[ob + s] = rne_bf16(v - bf16_f(hh));
    }
}

// ---------------- P3: RoPE trig table tt[pos-1][p] = (cos, sin) ---------------------
__global__ void k_trig(const float* __restrict__ fr, float* __restrict__ tt)
{
    const int idx = blockIdx.x * 256 + threadIdx.x;
    if (idx >= 3249 * 32) return;
    const int p = idx & 31;
    const float fi = (float)(idx >> 5);
    const float ty = floorf(fi / SIDE_);
    const float tx = fi - ty * SIDE_;
    float sn, cs;
    sincosf(tx * fr[p] + ty * fr[32 + p], &sn, &cs);
    tt[idx * 2]     = cs;
    tt[idx * 2 + 1] = sn;
}

// ---------------- K1: conv as 9 shifted GEMMs via split-bf16 MFMA -------------------
// grid (50, 8, 3cv), 256 thr (4 waves). wave = n-tile (16 co); 5 m-tiles {0,16,32,48,49}.
__global__ __launch_bounds__(256) void k_conv2(
    const unsigned short* __restrict__ xt_hi, const unsigned short* __restrict__ xt_lo,
    const unsigned short* __restrict__ wt_hi, const unsigned short* __restrict__ wt_lo,
    const float* __restrict__ bq, const float* __restrict__ bk, const float* __restrict__ bv,
    const float* __restrict__ tt,
    float* __restrict__ qr, unsigned short* __restrict__ khg,
    unsigned short* __restrict__ klg, unsigned short* __restrict__ vgT)
{
    const int h  = blockIdx.x;
    const int b  = blockIdx.y;
    const int cv = blockIdx.z;
    const int t  = threadIdx.x;
    const int l  = t & 63;
    const int nt = t >> 6;
    const int c  = l & 15;
    const int g  = l >> 4;

    __shared__ unsigned short vt[64 * 68];

    const float* bp = (cv == 0) ? bq : ((cv == 1) ? bk : bv);
    const int mstart[5] = {0, 16, 32, 48, 49};

    const f32x4 zero4 = {0.f, 0.f, 0.f, 0.f};
    f32x4 acc[5];
#pragma unroll
    for (int mt = 0; mt < 5; ++mt) acc[mt] = zero4;

#pragma unroll 1
    for (int chunk = 0; chunk < 2; ++chunk) {
#pragma unroll 1
        for (int khkw = 0; khkw < 9; ++khkw) {
            const int kh = khkw / 3, kw = khkw % 3;
            const int wb = ((cv * 18 + khkw * 2 + chunk) << 11) + (nt * 16 + c) * 32 + g * 8;
            const s16x8 bh = *(const s16x8*)(wt_hi + wb);
            const s16x8 bl = *(const s16x8*)(wt_lo + wb);
            const int ab0 = (((b * 52 + h + kh) * 68) + c + kw) * 64 + chunk * 32 + g * 8;
#pragma unroll
            for (int mt = 0; mt < 5; ++mt) {
                const int ai = ab0 + mstart[mt] * 64;
                const s16x8 ah = *(const s16x8*)(xt_hi + ai);
                const s16x8 al = *(const s16x8*)(xt_lo + ai);
                MFMA16(acc[mt], ah, bh);
                MFMA16(acc[mt], al, bh);
                MFMA16(acc[mt], ah, bl);
            }
        }
    }

    const int co = nt * 16 + c;
    const float bias = bp[co];

    if (cv == 2) {            // V: LDS transpose -> (B,C,NP) bf16, coalesced store
#pragma unroll
        for (int mt = 0; mt < 5; ++mt)
#pragma unroll
            for (int r = 0; r < 4; ++r) {
                const int mloc = mstart[mt] + g * 4 + r;
                vt[co * 68 + mloc] = rne_bf16(acc[mt][r] + bias);
            }
        __syncthreads();
        for (int s = t; s < 64 * 65; s += 256) {
            const int cc = s / 65, mm = s % 65;
            vgT[(size_t)(b * 64 + cc) * NP_ + h * 65 + mm] = vt[cc * 68 + mm];
        }
        return;
    }

    // q,k: bias + RoPE (pair partner via shfl_xor 1) + store
#pragma unroll
    for (int mt = 0; mt < 5; ++mt)
#pragma unroll
        for (int r = 0; r < 4; ++r) {
            const int mloc = mstart[mt] + g * 4 + r;
            const int pos  = h * 65 + mloc;
            float v = acc[mt][r] + bias;
            const float pr = __shfl_xor(v, 1);
            if (pos > 0) {
                const float2 cs2 = *(const float2*)(tt + ((size_t)(pos - 1) * 32 + (co >> 1)) * 2);
                v = (l & 1) ? (pr * cs2.y + v * cs2.x) : (v * cs2.x - pr * cs2.y);
            }
            if (cv == 0) {
                qr[(size_t)(b * N_ + pos) * 64 + co] = v;
            } else {
                const size_t idx = (size_t)(b * NP_ + pos) * 64 + co;
                const unsigned short hh = rne_bf16(v);
                khg[idx] = hh;
                klg[idx] = rne_bf16(v - bf16_f(hh));
            }
        }
}

// ---------------- K2: flash attention, double-buffered LDS KV + reg prefetch --------
// grid (8, 26), 512 thr. Wave wz owns q-rows [by*128 + wz*16, +16). Per tile:
// {ds_write staged regs -> buf[t&1]; ONE barrier; issue t+1 global loads (hidden under
// compute); compute buf[t&1]}. Read(t) is ordered before write(t+2) by barrier(t+1).
// Math identical to validated flash5.
__global__ __launch_bounds__(512) void k_flash6(
    const float* __restrict__ qr, const unsigned short* __restrict__ khg,
    const unsigned short* __restrict__ klg, const unsigned short* __restrict__ vgT,
    float* __restrict__ oo)
{
    const int b  = blockIdx.x;          // flat%8 == batch -> per-batch XCD pinning
    const int t  = threadIdx.x;
    const int wz = t >> 6;              // wave id 0..7
    const int l  = t & 63;
    const int c  = l & 15;
    const int g  = l >> 4;
    const int m0 = blockIdx.y * 128 + wz * 16;

    __shared__ __align__(16) unsigned short kbh[2][4096];   // 2x8KB K-hi [64key][64]swz
    __shared__ __align__(16) unsigned short kbl[2][4096];   // 2x8KB K-lo
    __shared__ __align__(16) unsigned short vb [2][4096];   // 2x8KB V [64ch][64key]swz
    __shared__ __align__(16) char psmem[32768];             // per-wave P hi/lo

    char* pwh = psmem + wz * 4096;
    char* pwl = psmem + wz * 4096 + 2048;

    // Q A-frags: row = lane&15 (m0+c), k = ks*32 + g*8 + j
    s16x8 qh[2], ql[2];
#pragma unroll
    for (int ks = 0; ks < 2; ++ks) {
        const float* qp = qr + ((size_t)(b * N_ + m0 + c) * 64 + ks * 32 + g * 8);
        const f32x4 f0 = *(const f32x4*)qp;
        const f32x4 f1 = *(const f32x4*)(qp + 4);
#pragma unroll
        for (int j = 0; j < 4; ++j) {
            const unsigned short h0 = rne_bf16(f0[j]);
            qh[ks][j]     = (short)h0;
            ql[ks][j]     = (short)rne_bf16(f0[j] - bf16_f(h0));
            const unsigned short h1 = rne_bf16(f1[j]);
            qh[ks][4 + j] = (short)h1;
            ql[ks][4 + j] = (short)rne_bf16(f1[j] - bf16_f(h1));
        }
    }

    const f32x4 zero4 = {0.f, 0.f, 0.f, 0.f};
    f32x4 osum[4];
#pragma unroll
    for (int ct = 0; ct < 4; ++ct) osum[ct] = zero4;
    float run_m[4], run_l[4];
#pragma unroll
    for (int r = 0; r < 4; ++r) { run_m[r] = -1e30f; run_l[r] = 0.f; }

    // staging: thread t handles 16B slot (row = t>>3, chunk = t&7)
    const int srow   = t >> 3;
    const int schunk = t & 7;
    const int sdst   = (srow * 128 + schunk * 16) ^ ((srow & 7) << 4);
    const unsigned short* kbase = khg + (size_t)(b * NP_) * 64;
    const unsigned short* lbase = klg + (size_t)(b * NP_) * 64;
    const unsigned short* vbase = vgT + (size_t)(b * 64 + srow) * NP_;

    // prologue: load tile 0 into staging regs
    s16x8 rk = *(const s16x8*)(kbase + t * 8);
    s16x8 rl = *(const s16x8*)(lbase + t * 8);
    s16x8 rv = *(const s16x8*)(vbase + schunk * 8);

    for (int tile = 0; tile < 51; ++tile) {
        const int n0  = tile << 6;
        const int cur = tile & 1;

        // commit staged regs to LDS buffer `cur`
        *(s16x8*)((char*)kbh[cur] + sdst) = rk;
        *(s16x8*)((char*)kbl[cur] + sdst) = rl;
        *(s16x8*)((char*)vb [cur] + sdst) = rv;
        __syncthreads();                      // buf[cur] staged; also fences read(t-1)

        if (tile < 50) {                      // prefetch next tile (hidden under compute)
            const int n1 = (tile + 1) << 6;
            rk = *(const s16x8*)(kbase + (size_t)n1 * 64 + t * 8);
            rl = *(const s16x8*)(lbase + (size_t)n1 * 64 + t * 8);
            rv = *(const s16x8*)(vbase + n1 + schunk * 8);
        }

        // ---- S = Q K^T (3-product split), K frags from LDS ----
        f32x4 s4[4];
#pragma unroll
        for (int nt = 0; nt < 4; ++nt) s4[nt] = zero4;
#pragma unroll
        for (int ks = 0; ks < 2; ++ks) {
#pragma unroll
            for (int nt = 0; nt < 4; ++nt) {
                const int krow = nt * 16 + c;
                const int koff = (krow * 128 + ks * 64 + g * 16) ^ ((krow & 7) << 4);
                const s16x8 kh = *(const s16x8*)((const char*)kbh[cur] + koff);
                const s16x8 kl = *(const s16x8*)((const char*)kbl[cur] + koff);
                MFMA16(s4[nt], qh[ks], kh);
                MFMA16(s4[nt], ql[ks], kh);
                MFMA16(s4[nt], qh[ks], kl);
            }
        }

        if (tile == 50) {                  // mask padded key columns
#pragma unroll
            for (int nt = 0; nt < 4; ++nt)
                if (n0 + nt * 16 + c >= N_) {
                    const f32x4 m4 = {-1e30f, -1e30f, -1e30f, -1e30f};
                    s4[nt] = m4;
                }
        }

        // ---- online softmax: row r across the 16 c-lanes of group g ----
        float corr[4];
#pragma unroll
        for (int r = 0; r < 4; ++r) {
            float tm = fmaxf(fmaxf(s4[0][r], s4[1][r]), fmaxf(s4[2][r], s4[3][r]));
            tm = fmaxf(tm, __shfl_xor(tm, 1));
            tm = fmaxf(tm, __shfl_xor(tm, 2));
            tm = fmaxf(tm, __shfl_xor(tm, 4));
            tm = fmaxf(tm, __shfl_xor(tm, 8));
            const float mnew = fmaxf(run_m[r], tm);
            corr[r] = __expf(run_m[r] - mnew);
            float ts = 0.f;
#pragma unroll
            for (int nt = 0; nt < 4; ++nt) {
                const float p = __expf(s4[nt][r] - mnew);
                s4[nt][r] = p;
                ts += p;
            }
            ts += __shfl_xor(ts, 1);
            ts += __shfl_xor(ts, 2);
            ts += __shfl_xor(ts, 4);
            ts += __shfl_xor(ts, 8);
            run_l[r] = run_l[r] * corr[r] + ts;
            run_m[r] = mnew;
        }
#pragma unroll
        for (int ct = 0; ct < 4; ++ct)
#pragma unroll
            for (int r = 0; r < 4; ++r) osum[ct][r] *= corr[r];

        // ---- P split -> per-wave LDS slice (swizzled [m][n]) ----
#pragma unroll
        for (int nt = 0; nt < 4; ++nt)
#pragma unroll
            for (int r = 0; r < 4; ++r) {
                const int m   = g * 4 + r;
                const int off = m * 128 + ((((nt * 16 + c) * 2)) ^ ((m & 7) << 4));
                const float p = s4[nt][r];
                const unsigned short ph = rne_bf16(p);
                *(unsigned short*)(pwh + off) = ph;
                *(unsigned short*)(pwl + off) = rne_bf16(p - bf16_f(ph));
            }

        // ---- O += P V, V frags from LDS ----
#pragma unroll
        for (int ks = 0; ks < 2; ++ks) {
            const int aoff = c * 128 + (((ks * 64 + g * 16)) ^ ((c & 7) << 4));
            const s16x8 pah = *(const s16x8*)(pwh + aoff);
            const s16x8 pal = *(const s16x8*)(pwl + aoff);
#pragma unroll
            for (int ct = 0; ct < 4; ++ct) {
                const int vrow = ct * 16 + c;
                const int voff = (vrow * 128 + ks * 64 + g * 16) ^ ((vrow & 7) << 4);
                const s16x8 vf = *(const s16x8*)((const char*)vb[cur] + voff);
                MFMA16(osum[ct], pah, vf);
                MFMA16(osum[ct], pal, vf);
            }
        }
    }

    // ---- epilogue: each wave owns its rows; direct normalize + store ----
#pragma unroll
    for (int ct = 0; ct < 4; ++ct)
#pragma unroll
        for (int r = 0; r < 4; ++r) {
            const int m = m0 + g * 4 + r;          // C/D row = g*4+r, col = ct*16+c
            if (m < N_) oo[(size_t)(b * N_ + m) * 64 + ct * 16 + c] = osum[ct][r] / run_l[r];
        }
}

// ---------------- K3: y = gamma*x + O^T, per-block partial sums (no atomics) --------
__global__ __launch_bounds__(256) void k_bnstats(
    const float* __restrict__ x, const float* __restrict__ oo,
    const float* __restrict__ gamma, float* __restrict__ yy, float* __restrict__ part)
{
    const int b    = blockIdx.y;
    const int m0   = blockIdx.x * 64;
    const int t    = threadIdx.x;
    const int lane = t & 63;
    const int blk  = blockIdx.y * 51 + blockIdx.x;
    __shared__ float ot[64 * 65];
    const float gm = gamma[0];
    {
        const int r4 = t >> 6;
#pragma unroll
        for (int i = 0; i < 16; ++i) {
            const int row = r4 + i * 4;
            const int m   = m0 + row;
            ot[row * 65 + lane] = (m < N_) ? oo[((size_t)b * N_ + m) * 64 + lane] : 0.f;
        }
    }
    __syncthreads();
    const int  m     = m0 + lane;
    const bool valid = (m < N_);
#pragma unroll
    for (int i = 0; i < 16; ++i) {
        const int c = (t >> 6) + (i << 2);
        float y = 0.f;
        if (valid) {
            const float xv = x[(size_t)(b * 64 + c) * N_ + m];
            y = gm * xv + ot[lane * 65 + c];
            yy[(size_t)(b * 64 + c) * N_ + m] = y;
        }
        float s1 = y, s2 = y * y;
#pragma unroll
        for (int d = 1; d < 64; d <<= 1) { s1 += __shfl_xor(s1, d); s2 += __shfl_xor(s2, d); }
        if (lane == 0) {
            part[(size_t)blk * 128 + c]      = s1;
            part[(size_t)blk * 128 + 64 + c] = s2;
        }
    }
}

// ---------------- K4: reduce partials, finalize scale/shift -------------------------
__global__ void k_bnfin(const float* __restrict__ part, const float* __restrict__ bnw,
                        const float* __restrict__ bnb, float* __restrict__ ss)
{
    const int c = threadIdx.x;              // 64
    float s1 = 0.f, s2 = 0.f;
    for (int k = 0; k < 408; ++k) {
        s1 += part[(size_t)k * 128 + c];
        s2 += part[(size_t)k * 128 + 64 + c];
    }
    const float cnt  = (float)(B_ * N_);
    const float mean = s1 / cnt;
    const float var  = s2 / cnt - mean * mean;
    const float sc   = bnw[c] * rsqrtf(var + EPS_);
    ss[c]      = sc;
    ss[64 + c] = bnb[c] - mean * sc;
}

// ---------------- K5: apply BN -------------------------------------------------------
__global__ __launch_bounds__(256) void k_bnapply(
    const float* __restrict__ yy, const float* __restrict__ ss, float* __restrict__ out)
{
    const int total = B_ * C_ * N_;
    for (int e = blockIdx.x * 256 + threadIdx.x; e < total; e += gridDim.x * 256) {
        const int c = (e / N_) & 63;
        out[e] = yy[e] * ss[c] + ss[64 + c];
    }
}

// ---------------- launch -------------------------------------------------------------
extern "C" void kernel_launch(void* const* d_in, const int* in_sizes, int n_in,
                              void* d_out, int out_size, void* d_ws, size_t ws_size,
                              hipStream_t stream) {
    const float* x     = (const float*)d_in[0];
    const float* wq    = (const float*)d_in[1];
    const float* bq    = (const float*)d_in[2];
    const float* wk    = (const float*)d_in[3];
    const float* bk    = (const float*)d_in[4];
    const float* wv    = (const float*)d_in[5];
    const float* bv    = (const float*)d_in[6];
    const float* fr    = (const float*)d_in[7];
    const float* gamma = (const float*)d_in[8];
    const float* bnw   = (const float*)d_in[9];
    const float* bnb   = (const float*)d_in[10];

    // ws layout (floats), total 6,352,064 f = 25.4 MB (<= proven 26.6 MB budget)
    float* wsf = (float*)d_ws;
    float*          qr    = wsf;                                  // 1,664,000
    unsigned short* khg   = (unsigned short*)(wsf + 1664000);     // 835,584 f each
    unsigned short* klg   = (unsigned short*)(wsf + 2499584);
    unsigned short* vgT   = (unsigned short*)(wsf + 3335168);
    float*          regB  = wsf + 4170752;                        // 2,128,960 f region
    unsigned short* xt_hi = (unsigned short*)regB;                // conv phase
    unsigned short* xt_lo = (unsigned short*)(regB + 905216);
    unsigned short* wt_hi = (unsigned short*)(regB + 1810432);
    unsigned short* wt_lo = (unsigned short*)(regB + 1865728);
    float*          tt    = regB + 1921024;                       // 207,936
    float*          oo    = regB;                                 // flash phase (1,664,000)
    float*          part  = wsf + 6299712;                        // 52,224
    float*          ss    = wsf + 6351936;                        // 128
    float*          yy    = qr;                                   // reuse after flash
    float*          outp  = (float*)d_out;

    k_wprep<<<432, 256, 0, stream>>>(wq, wk, wv, wt_hi, wt_lo);
    k_xprep<<<dim3(52, 8), 256, 0, stream>>>(x, xt_hi, xt_lo);
    k_trig<<<407, 256, 0, stream>>>(fr, tt);
    k_conv2<<<dim3(50, 8, 3), 256, 0, stream>>>(xt_hi, xt_lo, wt_hi, wt_lo,
                                                bq, bk, bv, tt, qr, khg, klg, vgT);
    k_flash6<<<dim3(8, 26), 512, 0, stream>>>(qr, khg, klg, vgT, oo);
    k_bnstats<<<dim3(51, 8), 256, 0, stream>>>(x, oo, gamma, yy, part);
    k_bnfin<<<1, 64, 0, stream>>>(part, bnw, bnb, ss);
    k_bnapply<<<1024, 256, 0, stream>>>(yy, ss, outp);
}